// Round 3
// baseline (24179.314 us; speedup 1.0000x reference)
//
#include <hip/hip_runtime.h>
#include <math.h>

// ---------------------------------------------------------------------------
// Equivariant 3D CNN (e3nn-style), 5 layers, 48^3 grid, batch 2.
// Layer irreps:
//  L0: 1ch -> 60ch (IR_B), gate -> 50ch (IR_C)
//  L1-3: 50 -> 60, gate -> 50
//  L4: 50 -> 7 (IR_D), then sum over (x,y,z) -> [2,7]
// Kernels are 5x5x5, built on device from tp weights (paths below) + linear
// self-connection at the center tap (radial basis vanishes exactly at r=0).
// NOTE: input order is INTERLEAVED per setup_inputs() dict order:
//   d_in[0]=x, d_in[1]=tp_w0, d_in[2]=lin_w0, d_in[3]=tp_w1, d_in[4]=lin_w1, ...
// ---------------------------------------------------------------------------

struct TpPath { int off, ci, co, m1, l1, i2, mo, lo; float alpha; };
struct LinPath { int off, ci, co, m1, l, mo; float norm; };

// alpha = 1/sqrt(m1*1*R_BASIS): m1=1 -> 0.70710678, m1=10 -> 0.22360680, m1=5 -> 0.31622777
__device__ __constant__ TpPath g_tp[19] = {
  // ---- Layer 0: IR_A(1) -> IR_B(60), base 0, 3 paths
  {0,  0,  0, 1, 0, 0, 10, 0, 0.70710678f},
  {20, 0, 20, 1, 0, 0, 10, 0, 0.70710678f},
  {40, 0, 45, 1, 0, 1,  5, 1, 0.70710678f},
  // ---- Layers 1-3: IR_C(50) -> IR_B(60), base 3, 12 paths
  {0,    0,  0, 10, 0, 0, 10, 0, 0.22360680f},
  {200,  0, 20, 10, 0, 0, 10, 0, 0.22360680f},
  {400,  0, 45, 10, 0, 1,  5, 1, 0.22360680f},
  {500, 10, 10, 10, 0, 0, 10, 0, 0.22360680f},
  {700, 10, 30, 10, 0, 1,  5, 1, 0.22360680f},
  {800, 20, 30,  5, 1, 0,  5, 1, 0.31622777f},
  {850, 20, 10,  5, 1, 1, 10, 0, 0.31622777f},
  {950, 20, 45,  5, 1, 1,  5, 1, 0.31622777f},
  {1000,35, 45,  5, 1, 0,  5, 1, 0.31622777f},
  {1050,35,  0,  5, 1, 1, 10, 0, 0.31622777f},
  {1150,35, 20,  5, 1, 1, 10, 0, 0.31622777f},
  {1250,35, 30,  5, 1, 1,  5, 1, 0.31622777f},
  // ---- Layer 4: IR_C(50) -> IR_D(7), base 15, 4 paths
  {0,    0, 1, 10, 0, 0, 6, 0, 0.22360680f},
  {120, 10, 0, 10, 0, 0, 1, 0, 0.22360680f},
  {140, 20, 0,  5, 1, 1, 1, 0, 0.31622777f},
  {150, 35, 1,  5, 1, 1, 6, 0, 0.31622777f},
};

// norm = 1/sqrt(m1)
__device__ __constant__ LinPath g_lin[9] = {
  // L0 base 0, 2
  {0,  0,  0, 1, 0, 10, 1.0f},
  {10, 0, 20, 1, 0, 10, 1.0f},
  // L1-3 base 2, 5
  {0,   0,  0, 10, 0, 10, 0.31622777f},
  {100, 0, 20, 10, 0, 10, 0.31622777f},
  {200,10, 10, 10, 0, 10, 0.31622777f},
  {300,20, 30,  5, 1,  5, 0.44721360f},
  {325,35, 45,  5, 1,  5, 0.44721360f},
  // L4 base 7, 2
  {0,  0, 1, 10, 0, 6, 0.31622777f},
  {60,10, 0, 10, 0, 1, 0.31622777f},
};

__device__ inline float sus_f(float t) { return t > 0.f ? __expf(-1.f / t) : 0.f; }

// One block per tp path: fill k[xyz][ci..][co..] = alpha * (emb . w) * shfac
__global__ void build_tp_kernel(const float* __restrict__ tw, float* __restrict__ kbuf,
                                int CIN, int COUT, int path_base) {
  TpPath p = g_tp[path_base + blockIdx.x];
  const int dl1 = 2 * p.l1 + 1, dlo = 2 * p.lo + 1;
  const int du = p.m1 * dl1, dw = p.mo * dlo;
  const int total = 125 * du * dw;
  const float C0 = 1.14136f * expf(2.0f);
  for (int e = threadIdx.x; e < total; e += blockDim.x) {
    int xyz = e / (du * dw);
    int rem = e % (du * dw);
    int ui = rem / dw, wk = rem % dw;
    int u = ui / dl1, i = ui % dl1;
    int w = wk / dlo, kk = wk % dlo;
    int kx = xyz / 25, ky = (xyz / 5) % 5, kz = xyz % 5;
    float cx = (float)(kx - 2), cy = (float)(ky - 2), cz = (float)(kz - 2);
    float d = sqrtf(cx * cx + cy * cy + cz * cz);
    // radial basis (smooth_finite, R_BASIS=2, rmax=2.5): d/step = 1.2*d
    float t = 1.2f * d;
    float e0 = C0 * sus_f(t) * sus_f(2.f - t);
    float e1 = C0 * sus_f(t - 1.f) * sus_f(3.f - t);
    float radial = e0 * tw[p.off + (0 * p.m1 + u) * p.mo + w] +
                   e1 * tw[p.off + (1 * p.m1 + u) * p.mo + w];
    // SH l=1 components in e3nn (y,z,x) order, component-normalized
    float invd = (d > 0.f) ? 1.f / d : 0.f;
    const float s3 = 1.7320508f;
    float sh1[3] = { s3 * cy * invd, s3 * cz * invd, s3 * cx * invd };
    float shfac;
    if (p.l1 == 0 && p.i2 == 0)      shfac = 1.f;                         // (0,0,0)
    else if (p.l1 == 0)              shfac = sh1[kk];                     // (0,1,1): cg=delta(j,k)
    else if (p.i2 == 0)              shfac = (i == kk) ? 1.f : 0.f;       // (1,0,1)
    else if (p.lo == 0)              shfac = sh1[i] * 0.57735027f;        // (1,1,0): eye/sqrt3
    else {                                                                // (1,1,1): eps/sqrt2
      if (i == kk) shfac = 0.f;
      else {
        int j = 3 - i - kk;
        float sgn = (j == (i + 1) % 3) ? 1.f : -1.f;
        shfac = sgn * sh1[j] * 0.70710678f;
      }
    }
    kbuf[(size_t)(xyz * CIN + p.ci + ui) * COUT + p.co + wk] = p.alpha * radial * shfac;
  }
}

// Write linear self-connection matrix M into center tap (xyz=62). Paths wrote
// exact zeros there (emb(0)=0), so stores reproduce .set(M) over zero-init.
__global__ void set_center_kernel(const float* __restrict__ lw, float* __restrict__ kbuf,
                                  int CIN, int COUT, int lin_base, int nlin) {
  for (int l = 0; l < nlin; l++) {
    LinPath q = g_lin[lin_base + l];
    int dl = 2 * q.l + 1;
    int tot = q.m1 * q.mo * dl;
    for (int e = threadIdx.x; e < tot; e += blockDim.x) {
      int u = e / (q.mo * dl);
      int r = e % (q.mo * dl);
      int w = r / dl, ii = r % dl;
      kbuf[(size_t)(62 * CIN + q.ci + u * dl + ii) * COUT + q.co + w * dl + ii] =
          q.norm * lw[q.off + u * q.mo + w];
    }
  }
}

__device__ inline void gate_write(float* __restrict__ o, const float* __restrict__ a) {
  // Gate: gelu(tanh approx, jax default) on 0:10, tanh on 10:20,
  // sigmoid(20:30) gates the 10 vectors at 30:60 -> out 50 channels
#pragma unroll
  for (int c = 0; c < 10; c++) {
    float x = a[c];
    float inner = 0.79788456f * (x + 0.044715f * x * x * x);
    o[c] = 0.5f * x * (1.f + tanhf(inner));
  }
#pragma unroll
  for (int c = 0; c < 10; c++) o[10 + c] = tanhf(a[10 + c]);
#pragma unroll
  for (int u = 0; u < 10; u++) {
    float g = 1.f / (1.f + __expf(-a[20 + u]));
    o[20 + u * 3 + 0] = a[30 + u * 3 + 0] * g;
    o[20 + u * 3 + 1] = a[30 + u * 3 + 1] * g;
    o[20 + u * 3 + 2] = a[30 + u * 3 + 2] * g;
  }
}

// Direct conv, channels-last [N][X][Y][Z][C], SAME pad 2, cross-correlation.
// One wave (64 thr) per (n, x, y-pair); thread = z, owns 2 y rows.
// MODE 0: gate epilogue -> 50ch out. MODE 1: 7ch + global sum reduction.
template <int CIN, int COUT, int MODE>
__global__ __launch_bounds__(64)
void conv_kernel(const float* __restrict__ in, const float* __restrict__ kw,
                 float* __restrict__ out) {
  constexpr int CH = (CIN >= 10) ? 10 : CIN;
  constexpr int NCH = CIN / CH;
  __shared__ float w_lds[5][CH][COUT];

  int bid = blockIdx.x;
  int yp = bid % 24;
  int x = (bid / 24) % 48;
  int n = bid / (24 * 48);
  int y0 = yp * 2;
  int z = threadIdx.x;
  bool zon = z < 48;

  float acc0[COUT], acc1[COUT];
#pragma unroll
  for (int c = 0; c < COUT; c++) { acc0[c] = 0.f; acc1[c] = 0.f; }

  for (int dx = 0; dx < 5; dx++) {
    int xin = x + dx - 2;
    if (xin < 0 || xin >= 48) continue;            // block-uniform
    for (int dy = 0; dy < 5; dy++) {
      int yin0 = y0 + dy - 2, yin1 = yin0 + 1;
      bool vy0 = (yin0 >= 0 && yin0 < 48);
      bool vy1 = (yin1 >= 0 && yin1 < 48);
      if (!vy0 && !vy1) continue;                  // block-uniform
      const float* base0 = in + ((size_t)((n * 48 + xin) * 48 + yin0) * 48) * CIN;
      const float* base1 = base0 + 48 * CIN;
      int plane = dx * 5 + dy;
      for (int cc = 0; cc < NCH; cc++) {
        __syncthreads();
        for (int idx = threadIdx.x; idx < 5 * CH * COUT; idx += 64) {
          int dz = idx / (CH * COUT);
          int r2 = idx % (CH * COUT);
          int cil = r2 / COUT, co = r2 % COUT;
          w_lds[dz][cil][co] = kw[(size_t)((plane * 5 + dz) * CIN + cc * CH + cil) * COUT + co];
        }
        __syncthreads();
#pragma unroll 1
        for (int dz = 0; dz < 5; dz++) {
          int zin = z + dz - 2;
          bool vz = zon && zin >= 0 && zin < 48;
#pragma unroll 1
          for (int cil = 0; cil < CH; cil++) {
            int ci = cc * CH + cil;
            float v0 = (vz && vy0) ? base0[(size_t)zin * CIN + ci] : 0.f;
            float v1 = (vz && vy1) ? base1[(size_t)zin * CIN + ci] : 0.f;
#pragma unroll
            for (int co = 0; co < COUT; co++) {
              acc0[co] += v0 * w_lds[dz][cil][co];
              acc1[co] += v1 * w_lds[dz][cil][co];
            }
          }
        }
      }
    }
  }

  if (MODE == 0) {
    if (zon) {
      float* o0 = out + ((size_t)((n * 48 + x) * 48 + y0) * 48 + z) * 50;
      float* o1 = o0 + (size_t)48 * 50;
      gate_write(o0, acc0);
      gate_write(o1, acc1);
    }
  } else {
    // layer 4: per-thread partial sums, wave-reduce, atomicAdd into d_out[n*7+c]
#pragma unroll
    for (int c = 0; c < COUT; c++) {
      float v = acc0[c] + acc1[c];   // inactive lanes contribute 0
      for (int off = 32; off >= 1; off >>= 1) v += __shfl_down(v, off);
      if (threadIdx.x == 0) atomicAdd(&out[n * 7 + c], v);
    }
  }
}

extern "C" void kernel_launch(void* const* d_in, const int* in_sizes, int n_in,
                              void* d_out, int out_size, void* d_ws, size_t ws_size,
                              hipStream_t stream) {
  // setup_inputs() dict order (INTERLEAVED): x, tp_w0, lin_w0, tp_w1, lin_w1, ...
  const float* x   = (const float*)d_in[0];
  const float* tw0 = (const float*)d_in[1];
  const float* lw0 = (const float*)d_in[2];
  const float* tw1 = (const float*)d_in[3];
  const float* lw1 = (const float*)d_in[4];
  const float* tw2 = (const float*)d_in[5];
  const float* lw2 = (const float*)d_in[6];
  const float* tw3 = (const float*)d_in[7];
  const float* lw3 = (const float*)d_in[8];
  const float* tw4 = (const float*)d_in[9];
  const float* lw4 = (const float*)d_in[10];

  float* ws = (float*)d_ws;
  // kernel buffers
  float* k0 = ws;                 // 125*1*60   = 7500
  float* k1 = k0 + 7500;          // 125*50*60  = 375000
  float* k2 = k1 + 375000;
  float* k3 = k2 + 375000;
  float* k4 = k3 + 375000;        // 125*50*7   = 43750
  // activations (50 ch, channels-last), 2*48^3*50 = 11,059,200 floats each
  float* actA = ws + 1200000;
  float* actB = actA + 11059200;

  // zero kernel buffers + output accumulator
  hipMemsetAsync(ws, 0, (size_t)1176250 * sizeof(float), stream);
  hipMemsetAsync(d_out, 0, (size_t)out_size * sizeof(float), stream);

  // build conv kernels
  build_tp_kernel<<<3, 128, 0, stream>>>(tw0, k0, 1, 60, 0);
  build_tp_kernel<<<12, 128, 0, stream>>>(tw1, k1, 50, 60, 3);
  build_tp_kernel<<<12, 128, 0, stream>>>(tw2, k2, 50, 60, 3);
  build_tp_kernel<<<12, 128, 0, stream>>>(tw3, k3, 50, 60, 3);
  build_tp_kernel<<<4, 128, 0, stream>>>(tw4, k4, 50, 7, 15);
  set_center_kernel<<<1, 256, 0, stream>>>(lw0, k0, 1, 60, 0, 2);
  set_center_kernel<<<1, 256, 0, stream>>>(lw1, k1, 50, 60, 2, 5);
  set_center_kernel<<<1, 256, 0, stream>>>(lw2, k2, 50, 60, 2, 5);
  set_center_kernel<<<1, 256, 0, stream>>>(lw3, k3, 50, 60, 2, 5);
  set_center_kernel<<<1, 256, 0, stream>>>(lw4, k4, 50, 7, 7, 2);

  const int grid = 2 * 48 * 24;   // (n, x, y-pair)
  conv_kernel<1, 60, 0><<<grid, 64, 0, stream>>>(x, k0, actA);
  conv_kernel<50, 60, 0><<<grid, 64, 0, stream>>>(actA, k1, actB);
  conv_kernel<50, 60, 0><<<grid, 64, 0, stream>>>(actB, k2, actA);
  conv_kernel<50, 60, 0><<<grid, 64, 0, stream>>>(actA, k3, actB);
  conv_kernel<50, 7, 1><<<grid, 64, 0, stream>>>(actB, k4, (float*)d_out);
}